// Round 11
// baseline (416.551 us; speedup 1.0000x reference)
//
#include <hip/hip_runtime.h>
#include <hip/hip_fp16.h>

constexpr int BLK = 256;

static inline int cdiv(long long a, int b) { return (int)((a + b - 1) / b); }

using v8h = __attribute__((ext_vector_type(8))) _Float16;
using v4f = __attribute__((ext_vector_type(4))) float;

// ---------------- utility ----------------

__global__ void zero_int(int* __restrict__ p, int n) {
    for (int i = blockIdx.x * blockDim.x + threadIdx.x; i < n; i += gridDim.x * blockDim.x)
        p[i] = 0;
}

// ---------------- degree / CSR build ----------------

__global__ void count_dst_off(const int* __restrict__ dst, int* __restrict__ cnt,
                              int* __restrict__ eoff, int E) {
    for (int i = blockIdx.x * blockDim.x + threadIdx.x; i < E; i += gridDim.x * blockDim.x)
        eoff[i] = atomicAdd(&cnt[dst[i]], 1);
}

// block scans 1024 elements (256 threads x 4); also emits dis = rsqrt(cnt+1)
__global__ void scan1_dis(const int* __restrict__ cnt, int* __restrict__ rowptr,
                          int* __restrict__ bsum, float* __restrict__ dis, int N) {
    __shared__ int ts[256];
    int tid = threadIdx.x;
    int base = blockIdx.x * 1024 + tid * 4;
    int v[4], s = 0;
#pragma unroll
    for (int i = 0; i < 4; ++i) {
        v[i] = (base + i < N) ? cnt[base + i] : 0;
        s += v[i];
        if (base + i < N) dis[base + i] = rsqrtf((float)v[i] + 1.0f);
    }
    ts[tid] = s;
    __syncthreads();
    for (int off = 1; off < 256; off <<= 1) {
        int t = 0;
        if (tid >= off) t = ts[tid - off];
        __syncthreads();
        if (tid >= off) ts[tid] += t;
        __syncthreads();
    }
    int run = ts[tid] - s;
#pragma unroll
    for (int i = 0; i < 4; ++i) {
        if (base + i < N) rowptr[base + i] = run;
        run += v[i];
    }
    if (tid == 255) bsum[blockIdx.x] = ts[255];
}

// wave shuffle-scan over block sums (nb <= 64) + zero the BN sums buffer
__global__ void scan2z(const int* __restrict__ bsum, int* __restrict__ boff, int nb,
                       float* __restrict__ sums) {
    int tid = threadIdx.x;  // 640 threads
    if (tid < 64) {
        int orig = (tid < nb) ? bsum[tid] : 0;
        int v = orig;
#pragma unroll
        for (int off = 1; off < 64; off <<= 1) {
            int t = __shfl_up(v, off, 64);
            if (tid >= off) v += t;
        }
        if (tid < nb) boff[tid] = v - orig;  // exclusive
    } else if (tid < 64 + 576) {
        sums[tid - 64] = 0.0f;
    }
}

__global__ void scan3(int* __restrict__ rowptr, const int* __restrict__ boff, int N, int E) {
    int i = blockIdx.x * blockDim.x + threadIdx.x;
    if (i < N) rowptr[i] += boff[i >> 10];
    if (i == 0) rowptr[N] = E;
}

// atomic-free scatter of 4-B src index: slot = rowptr[dst] + eoff (bijection)
__global__ void csr_fill(const int* __restrict__ src, const int* __restrict__ dst,
                         const int* __restrict__ eoff, const int* __restrict__ rowptr,
                         int* __restrict__ csrc, int E) {
    for (int i = blockIdx.x * blockDim.x + threadIdx.x; i < E; i += gridDim.x * blockDim.x) {
        csrc[rowptr[dst[i]] + eoff[i]] = src[i];   // plain store (nt regressed)
    }
}

// ---------------- MFMA GEMM: act(in)[N,K] @ W[K,96] (+bias) -----------------
// A: fp32 -> BN+ReLU -> fp16 frags in regs. B: W^T fp16 in LDS (one barrier).
// ACT: BN scale/shift computed in-block from (bnsums, gamma, beta).
// STATS: epilogue accumulates column sum/sumsq into osums.

template <int K, bool ACT, bool BIAS, bool HOUT, bool WOUT, bool STATS>
__global__ __launch_bounds__(256) void gemm96m(const float* __restrict__ in,
                                               const float* __restrict__ W,
                                               const float* __restrict__ bias,
                                               const float* __restrict__ bnsums,
                                               const float* __restrict__ gamma,
                                               const float* __restrict__ beta,
                                               float* __restrict__ out,
                                               _Float16* __restrict__ hout,
                                               float* __restrict__ osums, int N) {
    constexpr int NK = K / 32;
    constexpr int LDK = K + 8;
    __shared__ __align__(16) _Float16 Wt[96 * LDK];
    __shared__ __align__(16) float ssl[ACT ? 192 : 1];
    __shared__ float sb[STATS ? 192 : 1];
    const int tid = threadIdx.x;
    for (int idx = tid; idx < K * 96; idx += 256) {
        int k = idx / 96, n = idx - k * 96;
        Wt[n * LDK + k] = (_Float16)W[idx];
    }
    if (ACT && tid < 96) {
        float inv_n = 1.0f / (float)N;
        float mean = bnsums[tid] * inv_n;
        float var = bnsums[96 + tid] * inv_n - mean * mean;
        float sc = gamma[tid] * rsqrtf(var + 1e-5f);
        ssl[tid] = sc;
        ssl[96 + tid] = beta[tid] - mean * sc;
    }
    if (STATS && tid < 192) sb[tid] = 0.0f;
    __syncthreads();

    const int wave = tid >> 6, lane = tid & 63;
    const int quad = lane >> 4, lm = lane & 15;
    const int rbase = blockIdx.x * 64 + wave * 16;
    int arow = rbase + lm;
    arow = arow < N ? arow : N - 1;

    v8h afr[NK];
#pragma unroll
    for (int kc = 0; kc < NK; ++kc) {
        const float* p = &in[(long long)arow * K + kc * 32 + quad * 8];
        float4 p0 = *(const float4*)p;
        float4 p1 = *(const float4*)(p + 4);
        if (ACT) {
            int kk = kc * 32 + quad * 8;
            float4 sc0 = *(const float4*)&ssl[kk];
            float4 sc1 = *(const float4*)&ssl[kk + 4];
            float4 sh0 = *(const float4*)&ssl[96 + kk];
            float4 sh1 = *(const float4*)&ssl[96 + kk + 4];
            p0.x = fmaxf(fmaf(p0.x, sc0.x, sh0.x), 0.0f);
            p0.y = fmaxf(fmaf(p0.y, sc0.y, sh0.y), 0.0f);
            p0.z = fmaxf(fmaf(p0.z, sc0.z, sh0.z), 0.0f);
            p0.w = fmaxf(fmaf(p0.w, sc0.w, sh0.w), 0.0f);
            p1.x = fmaxf(fmaf(p1.x, sc1.x, sh1.x), 0.0f);
            p1.y = fmaxf(fmaf(p1.y, sc1.y, sh1.y), 0.0f);
            p1.z = fmaxf(fmaf(p1.z, sc1.z, sh1.z), 0.0f);
            p1.w = fmaxf(fmaf(p1.w, sc1.w, sh1.w), 0.0f);
        }
        v8h a;
        a[0] = (_Float16)p0.x; a[1] = (_Float16)p0.y;
        a[2] = (_Float16)p0.z; a[3] = (_Float16)p0.w;
        a[4] = (_Float16)p1.x; a[5] = (_Float16)p1.y;
        a[6] = (_Float16)p1.z; a[7] = (_Float16)p1.w;
        afr[kc] = a;
    }

    v4f acc[6];
#pragma unroll
    for (int t = 0; t < 6; ++t) {
        v4f c = {0.0f, 0.0f, 0.0f, 0.0f};
#pragma unroll
        for (int kc = 0; kc < NK; ++kc) {
            v8h b = *(const v8h*)&Wt[(t * 16 + lm) * LDK + kc * 32 + quad * 8];
            c = __builtin_amdgcn_mfma_f32_16x16x32_f16(afr[kc], b, c, 0, 0, 0);
        }
        acc[t] = c;
    }

    float ls[6], lq[6];
#pragma unroll
    for (int t = 0; t < 6; ++t) { ls[t] = 0.0f; lq[t] = 0.0f; }
#pragma unroll
    for (int t = 0; t < 6; ++t) {
        float bv = BIAS ? bias[t * 16 + lm] : 0.0f;
#pragma unroll
        for (int r = 0; r < 4; ++r) {
            int gr = rbase + quad * 4 + r;
            if (gr < N) {
                float o = acc[t][r] + bv;
                if (WOUT) out[(long long)gr * 96 + t * 16 + lm] = o;
                if (HOUT) hout[(long long)gr * 96 + t * 16 + lm] = (_Float16)o;
                if (STATS) { ls[t] += o; lq[t] += o * o; }
            }
        }
    }
    if (STATS) {
#pragma unroll
        for (int t = 0; t < 6; ++t) {
            ls[t] += __shfl_xor(ls[t], 16);
            ls[t] += __shfl_xor(ls[t], 32);
            lq[t] += __shfl_xor(lq[t], 16);
            lq[t] += __shfl_xor(lq[t], 32);
        }
        if (quad == 0) {
#pragma unroll
            for (int t = 0; t < 6; ++t) {
                atomicAdd(&sb[t * 16 + lm], ls[t]);
                atomicAdd(&sb[96 + t * 16 + lm], lq[t]);
            }
        }
        __syncthreads();
        if (tid < 192) atomicAdd(&osums[tid], sb[tid]);
    }
}

// ---------------- MFMA final GEMM: l2norm(act(in) @ Wp2[96,64] + bp2) -------

__global__ __launch_bounds__(256) void gemm_finalm(const float* __restrict__ in,
                                                   const float* __restrict__ W,
                                                   const float* __restrict__ bias,
                                                   const float* __restrict__ bnsums,
                                                   const float* __restrict__ gamma,
                                                   const float* __restrict__ beta,
                                                   float* __restrict__ out, int N) {
    constexpr int K = 96, NK = 3, LDK = K + 8;
    __shared__ __align__(16) _Float16 Wt[64 * LDK];
    __shared__ __align__(16) float ssl[192];
    const int tid = threadIdx.x;
    for (int idx = tid; idx < K * 64; idx += 256) {
        int k = idx / 64, n = idx - k * 64;
        Wt[n * LDK + k] = (_Float16)W[idx];
    }
    if (tid < 96) {
        float inv_n = 1.0f / (float)N;
        float mean = bnsums[tid] * inv_n;
        float var = bnsums[96 + tid] * inv_n - mean * mean;
        float sc = gamma[tid] * rsqrtf(var + 1e-5f);
        ssl[tid] = sc;
        ssl[96 + tid] = beta[tid] - mean * sc;
    }
    __syncthreads();

    const int wave = tid >> 6, lane = tid & 63;
    const int quad = lane >> 4, lm = lane & 15;
    const int rbase = blockIdx.x * 64 + wave * 16;
    int arow = rbase + lm;
    arow = arow < N ? arow : N - 1;

    v8h afr[NK];
#pragma unroll
    for (int kc = 0; kc < NK; ++kc) {
        const float* p = &in[(long long)arow * K + kc * 32 + quad * 8];
        float4 p0 = *(const float4*)p;
        float4 p1 = *(const float4*)(p + 4);
        int kk = kc * 32 + quad * 8;
        float4 sc0 = *(const float4*)&ssl[kk];
        float4 sc1 = *(const float4*)&ssl[kk + 4];
        float4 sh0 = *(const float4*)&ssl[96 + kk];
        float4 sh1 = *(const float4*)&ssl[96 + kk + 4];
        p0.x = fmaxf(fmaf(p0.x, sc0.x, sh0.x), 0.0f);
        p0.y = fmaxf(fmaf(p0.y, sc0.y, sh0.y), 0.0f);
        p0.z = fmaxf(fmaf(p0.z, sc0.z, sh0.z), 0.0f);
        p0.w = fmaxf(fmaf(p0.w, sc0.w, sh0.w), 0.0f);
        p1.x = fmaxf(fmaf(p1.x, sc1.x, sh1.x), 0.0f);
        p1.y = fmaxf(fmaf(p1.y, sc1.y, sh1.y), 0.0f);
        p1.z = fmaxf(fmaf(p1.z, sc1.z, sh1.z), 0.0f);
        p1.w = fmaxf(fmaf(p1.w, sc1.w, sh1.w), 0.0f);
        v8h a;
        a[0] = (_Float16)p0.x; a[1] = (_Float16)p0.y;
        a[2] = (_Float16)p0.z; a[3] = (_Float16)p0.w;
        a[4] = (_Float16)p1.x; a[5] = (_Float16)p1.y;
        a[6] = (_Float16)p1.z; a[7] = (_Float16)p1.w;
        afr[kc] = a;
    }

    v4f acc[4];
#pragma unroll
    for (int t = 0; t < 4; ++t) {
        v4f c = {0.0f, 0.0f, 0.0f, 0.0f};
#pragma unroll
        for (int kc = 0; kc < NK; ++kc) {
            v8h b = *(const v8h*)&Wt[(t * 16 + lm) * LDK + kc * 32 + quad * 8];
            c = __builtin_amdgcn_mfma_f32_16x16x32_f16(afr[kc], b, c, 0, 0, 0);
        }
        float bv = bias[t * 16 + lm];
        c[0] += bv; c[1] += bv; c[2] += bv; c[3] += bv;
        acc[t] = c;
    }

    float sq[4];
#pragma unroll
    for (int r = 0; r < 4; ++r) {
        float s = acc[0][r] * acc[0][r] + acc[1][r] * acc[1][r] +
                  acc[2][r] * acc[2][r] + acc[3][r] * acc[3][r];
#pragma unroll
        for (int m = 1; m < 16; m <<= 1) s += __shfl_xor(s, m, 64);
        sq[r] = 1.0f / fmaxf(sqrtf(s), 1e-12f);
    }
#pragma unroll
    for (int r = 0; r < 4; ++r) {
        int gr = rbase + quad * 4 + r;
        if (gr < N) {
#pragma unroll
            for (int t = 0; t < 4; ++t)
                out[(long long)gr * 64 + t * 16 + lm] = acc[t][r] * sq[r];
        }
    }
}

// ---------- CSR pull aggregation, channel-sliced (32 ch/pass, L2-resident) ----
// Pass p covers channels [c0, c0+32). Working set = N * 64 B = 3.2 MB < 4 MB
// per-XCD L2 (the full 9.6 MB hbuf overflows it -> L3). 4 threads/node, 8 ch
// (16 B) each; a node's 4 lanes gather one aligned 64-B line per edge.

__global__ __launch_bounds__(256) void agg32h(const __half* __restrict__ hxw,
                                              const int* __restrict__ rowptr,
                                              const int* __restrict__ csrc,
                                              const float* __restrict__ dis,
                                              const float* __restrict__ bias,
                                              float* __restrict__ out, int N, int c0) {
    int idx = blockIdx.x * 256 + threadIdx.x;
    if (idx >= N * 4) return;
    int n = idx >> 2, ch = c0 + (idx & 3) * 8;
    float dn = dis[n];
    float acc[8];
    {
        float dd = dn * dn;
        float4 g = *(const float4*)&hxw[(long long)n * 96 + ch];
        const __half2* hs = (const __half2*)&g;
#pragma unroll
        for (int k = 0; k < 4; ++k) {
            float2 f = __half22float2(hs[k]);
            acc[2 * k + 0] = fmaf(f.x, dd, bias[ch + 2 * k + 0]);
            acc[2 * k + 1] = fmaf(f.y, dd, bias[ch + 2 * k + 1]);
        }
    }
    int e = rowptr[n], e1 = rowptr[n + 1];
    for (; e + 7 < e1; e += 8) {
        int s[8];
        float w[8];
        float4 g[8];
#pragma unroll
        for (int j = 0; j < 8; ++j) s[j] = csrc[e + j];
#pragma unroll
        for (int j = 0; j < 8; ++j) w[j] = dis[s[j]] * dn;
#pragma unroll
        for (int j = 0; j < 8; ++j)
            g[j] = *(const float4*)&hxw[(long long)s[j] * 96 + ch];
#pragma unroll
        for (int j = 0; j < 8; ++j) {
            const __half2* h = (const __half2*)&g[j];
#pragma unroll
            for (int k = 0; k < 4; ++k) {
                float2 f = __half22float2(h[k]);
                acc[2 * k + 0] = fmaf(f.x, w[j], acc[2 * k + 0]);
                acc[2 * k + 1] = fmaf(f.y, w[j], acc[2 * k + 1]);
            }
        }
    }
    for (; e + 3 < e1; e += 4) {
        int s[4];
        float w[4];
        float4 g[4];
#pragma unroll
        for (int j = 0; j < 4; ++j) s[j] = csrc[e + j];
#pragma unroll
        for (int j = 0; j < 4; ++j) w[j] = dis[s[j]] * dn;
#pragma unroll
        for (int j = 0; j < 4; ++j)
            g[j] = *(const float4*)&hxw[(long long)s[j] * 96 + ch];
#pragma unroll
        for (int j = 0; j < 4; ++j) {
            const __half2* h = (const __half2*)&g[j];
#pragma unroll
            for (int k = 0; k < 4; ++k) {
                float2 f = __half22float2(h[k]);
                acc[2 * k + 0] = fmaf(f.x, w[j], acc[2 * k + 0]);
                acc[2 * k + 1] = fmaf(f.y, w[j], acc[2 * k + 1]);
            }
        }
    }
    for (; e < e1; ++e) {
        int s0 = csrc[e];
        float w0 = dis[s0] * dn;
        float4 g0 = *(const float4*)&hxw[(long long)s0 * 96 + ch];
        const __half2* h0 = (const __half2*)&g0;
#pragma unroll
        for (int k = 0; k < 4; ++k) {
            float2 f0 = __half22float2(h0[k]);
            acc[2 * k + 0] = fmaf(f0.x, w0, acc[2 * k + 0]);
            acc[2 * k + 1] = fmaf(f0.y, w0, acc[2 * k + 1]);
        }
    }
    float4 o0, o1;
    o0.x = acc[0]; o0.y = acc[1]; o0.z = acc[2]; o0.w = acc[3];
    o1.x = acc[4]; o1.y = acc[5]; o1.z = acc[6]; o1.w = acc[7];
    *(float4*)&out[(long long)n * 96 + ch] = o0;
    *(float4*)&out[(long long)n * 96 + ch + 4] = o1;
}

// ---------------- BN stats (coalesced grid-stride, for agg outputs) ----------

__global__ __launch_bounds__(256) void bn_stats96(const float* __restrict__ h,
                                                  float* __restrict__ sums, int N) {
    __shared__ float sb[192];
    const int tid = threadIdx.x;
    if (tid < 192) sb[tid] = 0.0f;
    __syncthreads();
    int g = blockIdx.x * 256 + tid;
    int total = N * 24, stride = gridDim.x * 256;  // stride multiple of 24
    float4 s4 = {0, 0, 0, 0}, q4 = {0, 0, 0, 0};
    int c4 = g % 24;
    for (int i = g; i < total; i += stride) {
        int n = i / 24;
        float4 v = *(const float4*)&h[n * 96 + 4 * c4];
        s4.x += v.x; s4.y += v.y; s4.z += v.z; s4.w += v.w;
        q4.x += v.x * v.x; q4.y += v.y * v.y; q4.z += v.z * v.z; q4.w += v.w * v.w;
    }
    atomicAdd(&sb[4 * c4 + 0], s4.x);
    atomicAdd(&sb[4 * c4 + 1], s4.y);
    atomicAdd(&sb[4 * c4 + 2], s4.z);
    atomicAdd(&sb[4 * c4 + 3], s4.w);
    atomicAdd(&sb[96 + 4 * c4 + 0], q4.x);
    atomicAdd(&sb[96 + 4 * c4 + 1], q4.y);
    atomicAdd(&sb[96 + 4 * c4 + 2], q4.z);
    atomicAdd(&sb[96 + 4 * c4 + 3], q4.w);
    __syncthreads();
    if (tid < 192) atomicAdd(&sums[tid], sb[tid]);
}

// ---------------- launch ----------------

extern "C" void kernel_launch(void* const* d_in, const int* in_sizes, int n_in,
                              void* d_out, int out_size, void* d_ws, size_t ws_size,
                              hipStream_t stream) {
    const float* x   = (const float*)d_in[0];
    const int*   ei  = (const int*)d_in[1];
    const float* W1  = (const float*)d_in[2];
    const float* b1  = (const float*)d_in[3];
    const float* g1  = (const float*)d_in[4];
    const float* be1 = (const float*)d_in[5];
    const float* W2  = (const float*)d_in[6];
    const float* b2  = (const float*)d_in[7];
    const float* g2  = (const float*)d_in[8];
    const float* be2 = (const float*)d_in[9];
    const float* Wp1 = (const float*)d_in[10];
    const float* bp1 = (const float*)d_in[11];
    const float* gp  = (const float*)d_in[12];
    const float* bep = (const float*)d_in[13];
    const float* Wp2 = (const float*)d_in[14];
    const float* bp2 = (const float*)d_in[15];

    const int N = in_sizes[0] / 128;   // 50000
    const int E = in_sizes[1] / 2;     // 800000
    const int* src = ei;
    const int* dst = ei + E;

    // workspace layout (~55 MB)
    char* w = (char*)d_ws;
    auto alloc = [&](size_t bytes) { char* p = w; w += (bytes + 15) & ~size_t(15); return p; };
    int*      cnt    = (int*)alloc((size_t)N * 4);
    int*      rowptr = (int*)alloc((size_t)(N + 1) * 4);
    int*      bsum   = (int*)alloc(64 * 4);
    int*      boff   = (int*)alloc(64 * 4);
    float*    dis    = (float*)alloc((size_t)N * 4);
    int*      eoff   = (int*)alloc((size_t)E * 4);
    int*      csrc   = (int*)alloc((size_t)E * 4);
    float*    buf1   = (float*)alloc((size_t)N * 96 * 4);
    float*    buf2   = (float*)alloc((size_t)N * 96 * 4);
    _Float16* hbuf   = (_Float16*)alloc((size_t)N * 96 * 2);
    float*    sums   = (float*)alloc(576 * 4);
    float* sums1 = sums, *sums2 = sums + 192, *sums3 = sums + 384;

    float* out = (float*)d_out;

    const int gE  = cdiv(E, BLK);                  // 3125 blocks, 1 edge/thread
    const int gG  = cdiv(N, 64);                   // 782 gemm blocks
    const int gA  = cdiv((long long)N * 4, BLK);   // 782 agg blocks per pass
    const int nb  = cdiv(N, 1024);                 // scan blocks (49)

    // CSR build (atomic-free 4-B scatter: slot = rowptr[dst] + eoff)
    zero_int<<<cdiv(N, BLK), BLK, 0, stream>>>(cnt, N);
    count_dst_off<<<gE, BLK, 0, stream>>>(dst, cnt, eoff, E);
    scan1_dis<<<nb, 256, 0, stream>>>(cnt, rowptr, bsum, dis, N);
    scan2z<<<1, 640, 0, stream>>>(bsum, boff, nb, sums);
    scan3<<<cdiv(N, BLK), BLK, 0, stream>>>(rowptr, boff, N, E);
    csr_fill<<<gE, BLK, 0, stream>>>(src, dst, eoff, rowptr, csrc, E);

    // layer 1: MFMA GEMM -> fp16 shadow; agg in 3 L2-resident channel passes
    gemm96m<128, false, false, true, false, false><<<gG, 256, 0, stream>>>(
        x, W1, nullptr, nullptr, nullptr, nullptr, nullptr, hbuf, nullptr, N);
    agg32h<<<gA, 256, 0, stream>>>((const __half*)hbuf, rowptr, csrc, dis, b1, buf2, N, 0);
    agg32h<<<gA, 256, 0, stream>>>((const __half*)hbuf, rowptr, csrc, dis, b1, buf2, N, 32);
    agg32h<<<gA, 256, 0, stream>>>((const __half*)hbuf, rowptr, csrc, dis, b1, buf2, N, 64);
    bn_stats96<<<512, 256, 0, stream>>>(buf2, sums1, N);

    // layer 2: BN1 finalize fused in-block; fp16 shadow out
    gemm96m<96, true, false, true, false, false><<<gG, 256, 0, stream>>>(
        buf2, W2, nullptr, sums1, g1, be1, nullptr, hbuf, nullptr, N);
    agg32h<<<gA, 256, 0, stream>>>((const __half*)hbuf, rowptr, csrc, dis, b2, buf2, N, 0);
    agg32h<<<gA, 256, 0, stream>>>((const __half*)hbuf, rowptr, csrc, dis, b2, buf2, N, 32);
    agg32h<<<gA, 256, 0, stream>>>((const __half*)hbuf, rowptr, csrc, dis, b2, buf2, N, 64);
    bn_stats96<<<512, 256, 0, stream>>>(buf2, sums2, N);

    // projector linear 1: BN2 finalize fused; fp32 out; BN3 stats fused
    gemm96m<96, true, true, false, true, true><<<gG, 256, 0, stream>>>(
        buf2, Wp1, bp1, sums2, g2, be2, buf1, nullptr, sums3, N);

    // projector linear 2: BN3 finalize fused + bias + L2 normalize
    gemm_finalm<<<gG, 256, 0, stream>>>(buf1, Wp2, bp2, sums3, gp, bep, out, N);
}

// Round 12
// 358.116 us; speedup vs baseline: 1.1632x; 1.1632x over previous
//
#include <hip/hip_runtime.h>
#include <hip/hip_fp16.h>

constexpr int BLK = 256;

static inline int cdiv(long long a, int b) { return (int)((a + b - 1) / b); }

using v8h = __attribute__((ext_vector_type(8))) _Float16;
using v4f = __attribute__((ext_vector_type(4))) float;

// ---------------- utility ----------------

__global__ void zero_int(int* __restrict__ p, int n) {
    for (int i = blockIdx.x * blockDim.x + threadIdx.x; i < n; i += gridDim.x * blockDim.x)
        p[i] = 0;
}

// ---------------- degree / CSR build ----------------

__global__ void count_dst_off(const int* __restrict__ dst, int* __restrict__ cnt,
                              int* __restrict__ eoff, int E) {
    for (int i = blockIdx.x * blockDim.x + threadIdx.x; i < E; i += gridDim.x * blockDim.x)
        eoff[i] = atomicAdd(&cnt[dst[i]], 1);
}

// block scans 1024 elements (256 threads x 4); also emits dis = rsqrt(cnt+1)
__global__ void scan1_dis(const int* __restrict__ cnt, int* __restrict__ rowptr,
                          int* __restrict__ bsum, float* __restrict__ dis, int N) {
    __shared__ int ts[256];
    int tid = threadIdx.x;
    int base = blockIdx.x * 1024 + tid * 4;
    int v[4], s = 0;
#pragma unroll
    for (int i = 0; i < 4; ++i) {
        v[i] = (base + i < N) ? cnt[base + i] : 0;
        s += v[i];
        if (base + i < N) dis[base + i] = rsqrtf((float)v[i] + 1.0f);
    }
    ts[tid] = s;
    __syncthreads();
    for (int off = 1; off < 256; off <<= 1) {
        int t = 0;
        if (tid >= off) t = ts[tid - off];
        __syncthreads();
        if (tid >= off) ts[tid] += t;
        __syncthreads();
    }
    int run = ts[tid] - s;
#pragma unroll
    for (int i = 0; i < 4; ++i) {
        if (base + i < N) rowptr[base + i] = run;
        run += v[i];
    }
    if (tid == 255) bsum[blockIdx.x] = ts[255];
}

// wave shuffle-scan over block sums (nb <= 64) + zero the BN sums buffer
__global__ void scan2z(const int* __restrict__ bsum, int* __restrict__ boff, int nb,
                       float* __restrict__ sums) {
    int tid = threadIdx.x;  // 640 threads
    if (tid < 64) {
        int orig = (tid < nb) ? bsum[tid] : 0;
        int v = orig;
#pragma unroll
        for (int off = 1; off < 64; off <<= 1) {
            int t = __shfl_up(v, off, 64);
            if (tid >= off) v += t;
        }
        if (tid < nb) boff[tid] = v - orig;  // exclusive
    } else if (tid < 64 + 576) {
        sums[tid - 64] = 0.0f;
    }
}

__global__ void scan3(int* __restrict__ rowptr, const int* __restrict__ boff, int N, int E) {
    int i = blockIdx.x * blockDim.x + threadIdx.x;
    if (i < N) rowptr[i] += boff[i >> 10];
    if (i == 0) rowptr[N] = E;
}

// atomic-free scatter of 4-B src index: slot = rowptr[dst] + eoff (bijection)
__global__ void csr_fill(const int* __restrict__ src, const int* __restrict__ dst,
                         const int* __restrict__ eoff, const int* __restrict__ rowptr,
                         int* __restrict__ csrc, int E) {
    for (int i = blockIdx.x * blockDim.x + threadIdx.x; i < E; i += gridDim.x * blockDim.x) {
        csrc[rowptr[dst[i]] + eoff[i]] = src[i];   // plain store (nt regressed R10)
    }
}

// ---------------- MFMA GEMM: act(in)[N,K] @ W[K,96] (+bias) -----------------
// A: fp32 -> BN+ReLU -> fp16 frags in regs. B: W^T fp16 in LDS (one barrier).
// ACT: BN scale/shift computed in-block from (bnsums, gamma, beta).
// STATS: epilogue accumulates column sum/sumsq into osums.

template <int K, bool ACT, bool BIAS, bool HOUT, bool WOUT, bool STATS>
__global__ __launch_bounds__(256) void gemm96m(const float* __restrict__ in,
                                               const float* __restrict__ W,
                                               const float* __restrict__ bias,
                                               const float* __restrict__ bnsums,
                                               const float* __restrict__ gamma,
                                               const float* __restrict__ beta,
                                               float* __restrict__ out,
                                               _Float16* __restrict__ hout,
                                               float* __restrict__ osums, int N) {
    constexpr int NK = K / 32;
    constexpr int LDK = K + 8;
    __shared__ __align__(16) _Float16 Wt[96 * LDK];
    __shared__ __align__(16) float ssl[ACT ? 192 : 1];
    __shared__ float sb[STATS ? 192 : 1];
    const int tid = threadIdx.x;
    for (int idx = tid; idx < K * 96; idx += 256) {
        int k = idx / 96, n = idx - k * 96;
        Wt[n * LDK + k] = (_Float16)W[idx];
    }
    if (ACT && tid < 96) {
        float inv_n = 1.0f / (float)N;
        float mean = bnsums[tid] * inv_n;
        float var = bnsums[96 + tid] * inv_n - mean * mean;
        float sc = gamma[tid] * rsqrtf(var + 1e-5f);
        ssl[tid] = sc;
        ssl[96 + tid] = beta[tid] - mean * sc;
    }
    if (STATS && tid < 192) sb[tid] = 0.0f;
    __syncthreads();

    const int wave = tid >> 6, lane = tid & 63;
    const int quad = lane >> 4, lm = lane & 15;
    const int rbase = blockIdx.x * 64 + wave * 16;
    int arow = rbase + lm;
    arow = arow < N ? arow : N - 1;

    v8h afr[NK];
#pragma unroll
    for (int kc = 0; kc < NK; ++kc) {
        const float* p = &in[(long long)arow * K + kc * 32 + quad * 8];
        float4 p0 = *(const float4*)p;
        float4 p1 = *(const float4*)(p + 4);
        if (ACT) {
            int kk = kc * 32 + quad * 8;
            float4 sc0 = *(const float4*)&ssl[kk];
            float4 sc1 = *(const float4*)&ssl[kk + 4];
            float4 sh0 = *(const float4*)&ssl[96 + kk];
            float4 sh1 = *(const float4*)&ssl[96 + kk + 4];
            p0.x = fmaxf(fmaf(p0.x, sc0.x, sh0.x), 0.0f);
            p0.y = fmaxf(fmaf(p0.y, sc0.y, sh0.y), 0.0f);
            p0.z = fmaxf(fmaf(p0.z, sc0.z, sh0.z), 0.0f);
            p0.w = fmaxf(fmaf(p0.w, sc0.w, sh0.w), 0.0f);
            p1.x = fmaxf(fmaf(p1.x, sc1.x, sh1.x), 0.0f);
            p1.y = fmaxf(fmaf(p1.y, sc1.y, sh1.y), 0.0f);
            p1.z = fmaxf(fmaf(p1.z, sc1.z, sh1.z), 0.0f);
            p1.w = fmaxf(fmaf(p1.w, sc1.w, sh1.w), 0.0f);
        }
        v8h a;
        a[0] = (_Float16)p0.x; a[1] = (_Float16)p0.y;
        a[2] = (_Float16)p0.z; a[3] = (_Float16)p0.w;
        a[4] = (_Float16)p1.x; a[5] = (_Float16)p1.y;
        a[6] = (_Float16)p1.z; a[7] = (_Float16)p1.w;
        afr[kc] = a;
    }

    v4f acc[6];
#pragma unroll
    for (int t = 0; t < 6; ++t) {
        v4f c = {0.0f, 0.0f, 0.0f, 0.0f};
#pragma unroll
        for (int kc = 0; kc < NK; ++kc) {
            v8h b = *(const v8h*)&Wt[(t * 16 + lm) * LDK + kc * 32 + quad * 8];
            c = __builtin_amdgcn_mfma_f32_16x16x32_f16(afr[kc], b, c, 0, 0, 0);
        }
        acc[t] = c;
    }

    float ls[6], lq[6];
#pragma unroll
    for (int t = 0; t < 6; ++t) { ls[t] = 0.0f; lq[t] = 0.0f; }
#pragma unroll
    for (int t = 0; t < 6; ++t) {
        float bv = BIAS ? bias[t * 16 + lm] : 0.0f;
#pragma unroll
        for (int r = 0; r < 4; ++r) {
            int gr = rbase + quad * 4 + r;
            if (gr < N) {
                float o = acc[t][r] + bv;
                if (WOUT) out[(long long)gr * 96 + t * 16 + lm] = o;
                if (HOUT) hout[(long long)gr * 96 + t * 16 + lm] = (_Float16)o;
                if (STATS) { ls[t] += o; lq[t] += o * o; }
            }
        }
    }
    if (STATS) {
#pragma unroll
        for (int t = 0; t < 6; ++t) {
            ls[t] += __shfl_xor(ls[t], 16);
            ls[t] += __shfl_xor(ls[t], 32);
            lq[t] += __shfl_xor(lq[t], 16);
            lq[t] += __shfl_xor(lq[t], 32);
        }
        if (quad == 0) {
#pragma unroll
            for (int t = 0; t < 6; ++t) {
                atomicAdd(&sb[t * 16 + lm], ls[t]);
                atomicAdd(&sb[96 + t * 16 + lm], lq[t]);
            }
        }
        __syncthreads();
        if (tid < 192) atomicAdd(&osums[tid], sb[tid]);
    }
}

// ---------------- MFMA final GEMM: l2norm(act(in) @ Wp2[96,64] + bp2) -------

__global__ __launch_bounds__(256) void gemm_finalm(const float* __restrict__ in,
                                                   const float* __restrict__ W,
                                                   const float* __restrict__ bias,
                                                   const float* __restrict__ bnsums,
                                                   const float* __restrict__ gamma,
                                                   const float* __restrict__ beta,
                                                   float* __restrict__ out, int N) {
    constexpr int K = 96, NK = 3, LDK = K + 8;
    __shared__ __align__(16) _Float16 Wt[64 * LDK];
    __shared__ __align__(16) float ssl[192];
    const int tid = threadIdx.x;
    for (int idx = tid; idx < K * 64; idx += 256) {
        int k = idx / 64, n = idx - k * 64;
        Wt[n * LDK + k] = (_Float16)W[idx];
    }
    if (tid < 96) {
        float inv_n = 1.0f / (float)N;
        float mean = bnsums[tid] * inv_n;
        float var = bnsums[96 + tid] * inv_n - mean * mean;
        float sc = gamma[tid] * rsqrtf(var + 1e-5f);
        ssl[tid] = sc;
        ssl[96 + tid] = beta[tid] - mean * sc;
    }
    __syncthreads();

    const int wave = tid >> 6, lane = tid & 63;
    const int quad = lane >> 4, lm = lane & 15;
    const int rbase = blockIdx.x * 64 + wave * 16;
    int arow = rbase + lm;
    arow = arow < N ? arow : N - 1;

    v8h afr[NK];
#pragma unroll
    for (int kc = 0; kc < NK; ++kc) {
        const float* p = &in[(long long)arow * K + kc * 32 + quad * 8];
        float4 p0 = *(const float4*)p;
        float4 p1 = *(const float4*)(p + 4);
        int kk = kc * 32 + quad * 8;
        float4 sc0 = *(const float4*)&ssl[kk];
        float4 sc1 = *(const float4*)&ssl[kk + 4];
        float4 sh0 = *(const float4*)&ssl[96 + kk];
        float4 sh1 = *(const float4*)&ssl[96 + kk + 4];
        p0.x = fmaxf(fmaf(p0.x, sc0.x, sh0.x), 0.0f);
        p0.y = fmaxf(fmaf(p0.y, sc0.y, sh0.y), 0.0f);
        p0.z = fmaxf(fmaf(p0.z, sc0.z, sh0.z), 0.0f);
        p0.w = fmaxf(fmaf(p0.w, sc0.w, sh0.w), 0.0f);
        p1.x = fmaxf(fmaf(p1.x, sc1.x, sh1.x), 0.0f);
        p1.y = fmaxf(fmaf(p1.y, sc1.y, sh1.y), 0.0f);
        p1.z = fmaxf(fmaf(p1.z, sc1.z, sh1.z), 0.0f);
        p1.w = fmaxf(fmaf(p1.w, sc1.w, sh1.w), 0.0f);
        v8h a;
        a[0] = (_Float16)p0.x; a[1] = (_Float16)p0.y;
        a[2] = (_Float16)p0.z; a[3] = (_Float16)p0.w;
        a[4] = (_Float16)p1.x; a[5] = (_Float16)p1.y;
        a[6] = (_Float16)p1.z; a[7] = (_Float16)p1.w;
        afr[kc] = a;
    }

    v4f acc[4];
#pragma unroll
    for (int t = 0; t < 4; ++t) {
        v4f c = {0.0f, 0.0f, 0.0f, 0.0f};
#pragma unroll
        for (int kc = 0; kc < NK; ++kc) {
            v8h b = *(const v8h*)&Wt[(t * 16 + lm) * LDK + kc * 32 + quad * 8];
            c = __builtin_amdgcn_mfma_f32_16x16x32_f16(afr[kc], b, c, 0, 0, 0);
        }
        float bv = bias[t * 16 + lm];
        c[0] += bv; c[1] += bv; c[2] += bv; c[3] += bv;
        acc[t] = c;
    }

    float sq[4];
#pragma unroll
    for (int r = 0; r < 4; ++r) {
        float s = acc[0][r] * acc[0][r] + acc[1][r] * acc[1][r] +
                  acc[2][r] * acc[2][r] + acc[3][r] * acc[3][r];
#pragma unroll
        for (int m = 1; m < 16; m <<= 1) s += __shfl_xor(s, m, 64);
        sq[r] = 1.0f / fmaxf(sqrtf(s), 1e-12f);
    }
#pragma unroll
    for (int r = 0; r < 4; ++r) {
        int gr = rbase + quad * 4 + r;
        if (gr < N) {
#pragma unroll
            for (int t = 0; t < 4; ++t)
                out[(long long)gr * 64 + t * 16 + lm] = acc[t][r] * sq[r];
        }
    }
}

// -------- CSR pull aggregation, fp16 gather, TWO nodes per thread -----------
// Thread handles 8 channels of nodes (2g, 2g+1); edge loops interleaved 4+4 ->
// two independent miss chains in flight + halved tail imbalance.

__device__ __forceinline__ void acc_edge(float* acc, const __half2* h, float w) {
#pragma unroll
    for (int k = 0; k < 4; ++k) {
        float2 f = __half22float2(h[k]);
        acc[2 * k + 0] = fmaf(f.x, w, acc[2 * k + 0]);
        acc[2 * k + 1] = fmaf(f.y, w, acc[2 * k + 1]);
    }
}

__global__ __launch_bounds__(256) void agg96h2(const __half* __restrict__ hxw,
                                               const int* __restrict__ rowptr,
                                               const int* __restrict__ csrc,
                                               const float* __restrict__ dis,
                                               const float* __restrict__ bias,
                                               float* __restrict__ out, int N) {
    int nPair = (N + 1) >> 1;
    int idx = blockIdx.x * 256 + threadIdx.x;
    if (idx >= nPair * 12) return;
    int g = idx / 12, c8 = idx % 12;
    int nA = 2 * g, nB = 2 * g + 1;
    bool hasB = nB < N;
    int ch = c8 * 8;

    float dnA = dis[nA];
    float dnB = hasB ? dis[nB] : 0.0f;
    float accA[8], accB[8];
    {
        float ddA = dnA * dnA;
        float4 gA = *(const float4*)&hxw[(long long)nA * 96 + ch];
        const __half2* hA = (const __half2*)&gA;
#pragma unroll
        for (int k = 0; k < 4; ++k) {
            float2 f = __half22float2(hA[k]);
            accA[2 * k + 0] = fmaf(f.x, ddA, bias[ch + 2 * k + 0]);
            accA[2 * k + 1] = fmaf(f.y, ddA, bias[ch + 2 * k + 1]);
        }
    }
    if (hasB) {
        float ddB = dnB * dnB;
        float4 gB = *(const float4*)&hxw[(long long)nB * 96 + ch];
        const __half2* hB = (const __half2*)&gB;
#pragma unroll
        for (int k = 0; k < 4; ++k) {
            float2 f = __half22float2(hB[k]);
            accB[2 * k + 0] = fmaf(f.x, ddB, bias[ch + 2 * k + 0]);
            accB[2 * k + 1] = fmaf(f.y, ddB, bias[ch + 2 * k + 1]);
        }
    }

    int eA = rowptr[nA], eA1 = rowptr[nA + 1];
    int eB = hasB ? eA1 : 0, eB1 = hasB ? rowptr[nB + 1] : 0;

    // interleaved 4+4: two independent chains
    while (eA + 3 < eA1 && eB + 3 < eB1) {
        int sA[4], sB[4];
#pragma unroll
        for (int j = 0; j < 4; ++j) sA[j] = csrc[eA + j];
#pragma unroll
        for (int j = 0; j < 4; ++j) sB[j] = csrc[eB + j];
        float wA[4], wB[4];
#pragma unroll
        for (int j = 0; j < 4; ++j) wA[j] = dis[sA[j]] * dnA;
#pragma unroll
        for (int j = 0; j < 4; ++j) wB[j] = dis[sB[j]] * dnB;
        float4 gA[4], gB[4];
#pragma unroll
        for (int j = 0; j < 4; ++j) gA[j] = *(const float4*)&hxw[(long long)sA[j] * 96 + ch];
#pragma unroll
        for (int j = 0; j < 4; ++j) gB[j] = *(const float4*)&hxw[(long long)sB[j] * 96 + ch];
#pragma unroll
        for (int j = 0; j < 4; ++j) acc_edge(accA, (const __half2*)&gA[j], wA[j]);
#pragma unroll
        for (int j = 0; j < 4; ++j) acc_edge(accB, (const __half2*)&gB[j], wB[j]);
        eA += 4; eB += 4;
    }
    // drain A (unroll 4 then scalar)
    for (; eA + 3 < eA1; eA += 4) {
        int s[4];
        float w[4];
        float4 g[4];
#pragma unroll
        for (int j = 0; j < 4; ++j) s[j] = csrc[eA + j];
#pragma unroll
        for (int j = 0; j < 4; ++j) w[j] = dis[s[j]] * dnA;
#pragma unroll
        for (int j = 0; j < 4; ++j) g[j] = *(const float4*)&hxw[(long long)s[j] * 96 + ch];
#pragma unroll
        for (int j = 0; j < 4; ++j) acc_edge(accA, (const __half2*)&g[j], w[j]);
    }
    for (; eA < eA1; ++eA) {
        int s0 = csrc[eA];
        float w0 = dis[s0] * dnA;
        float4 g0 = *(const float4*)&hxw[(long long)s0 * 96 + ch];
        acc_edge(accA, (const __half2*)&g0, w0);
    }
    // drain B
    for (; eB + 3 < eB1; eB += 4) {
        int s[4];
        float w[4];
        float4 g[4];
#pragma unroll
        for (int j = 0; j < 4; ++j) s[j] = csrc[eB + j];
#pragma unroll
        for (int j = 0; j < 4; ++j) w[j] = dis[s[j]] * dnB;
#pragma unroll
        for (int j = 0; j < 4; ++j) g[j] = *(const float4*)&hxw[(long long)s[j] * 96 + ch];
#pragma unroll
        for (int j = 0; j < 4; ++j) acc_edge(accB, (const __half2*)&g[j], w[j]);
    }
    for (; eB < eB1; ++eB) {
        int s0 = csrc[eB];
        float w0 = dis[s0] * dnB;
        float4 g0 = *(const float4*)&hxw[(long long)s0 * 96 + ch];
        acc_edge(accB, (const __half2*)&g0, w0);
    }

    float4 o0, o1;
    o0.x = accA[0]; o0.y = accA[1]; o0.z = accA[2]; o0.w = accA[3];
    o1.x = accA[4]; o1.y = accA[5]; o1.z = accA[6]; o1.w = accA[7];
    *(float4*)&out[(long long)nA * 96 + ch] = o0;
    *(float4*)&out[(long long)nA * 96 + ch + 4] = o1;
    if (hasB) {
        o0.x = accB[0]; o0.y = accB[1]; o0.z = accB[2]; o0.w = accB[3];
        o1.x = accB[4]; o1.y = accB[5]; o1.z = accB[6]; o1.w = accB[7];
        *(float4*)&out[(long long)nB * 96 + ch] = o0;
        *(float4*)&out[(long long)nB * 96 + ch + 4] = o1;
    }
}

// ---------------- BN stats (coalesced grid-stride, for agg outputs) ----------

__global__ __launch_bounds__(256) void bn_stats96(const float* __restrict__ h,
                                                  float* __restrict__ sums, int N) {
    __shared__ float sb[192];
    const int tid = threadIdx.x;
    if (tid < 192) sb[tid] = 0.0f;
    __syncthreads();
    int g = blockIdx.x * 256 + tid;
    int total = N * 24, stride = gridDim.x * 256;  // stride multiple of 24
    float4 s4 = {0, 0, 0, 0}, q4 = {0, 0, 0, 0};
    int c4 = g % 24;
    for (int i = g; i < total; i += stride) {
        int n = i / 24;
        float4 v = *(const float4*)&h[n * 96 + 4 * c4];
        s4.x += v.x; s4.y += v.y; s4.z += v.z; s4.w += v.w;
        q4.x += v.x * v.x; q4.y += v.y * v.y; q4.z += v.z * v.z; q4.w += v.w * v.w;
    }
    atomicAdd(&sb[4 * c4 + 0], s4.x);
    atomicAdd(&sb[4 * c4 + 1], s4.y);
    atomicAdd(&sb[4 * c4 + 2], s4.z);
    atomicAdd(&sb[4 * c4 + 3], s4.w);
    atomicAdd(&sb[96 + 4 * c4 + 0], q4.x);
    atomicAdd(&sb[96 + 4 * c4 + 1], q4.y);
    atomicAdd(&sb[96 + 4 * c4 + 2], q4.z);
    atomicAdd(&sb[96 + 4 * c4 + 3], q4.w);
    __syncthreads();
    if (tid < 192) atomicAdd(&sums[tid], sb[tid]);
}

// ---------------- launch ----------------

extern "C" void kernel_launch(void* const* d_in, const int* in_sizes, int n_in,
                              void* d_out, int out_size, void* d_ws, size_t ws_size,
                              hipStream_t stream) {
    const float* x   = (const float*)d_in[0];
    const int*   ei  = (const int*)d_in[1];
    const float* W1  = (const float*)d_in[2];
    const float* b1  = (const float*)d_in[3];
    const float* g1  = (const float*)d_in[4];
    const float* be1 = (const float*)d_in[5];
    const float* W2  = (const float*)d_in[6];
    const float* b2  = (const float*)d_in[7];
    const float* g2  = (const float*)d_in[8];
    const float* be2 = (const float*)d_in[9];
    const float* Wp1 = (const float*)d_in[10];
    const float* bp1 = (const float*)d_in[11];
    const float* gp  = (const float*)d_in[12];
    const float* bep = (const float*)d_in[13];
    const float* Wp2 = (const float*)d_in[14];
    const float* bp2 = (const float*)d_in[15];

    const int N = in_sizes[0] / 128;   // 50000
    const int E = in_sizes[1] / 2;     // 800000
    const int* src = ei;
    const int* dst = ei + E;

    // workspace layout (~55 MB)
    char* w = (char*)d_ws;
    auto alloc = [&](size_t bytes) { char* p = w; w += (bytes + 15) & ~size_t(15); return p; };
    int*      cnt    = (int*)alloc((size_t)N * 4);
    int*      rowptr = (int*)alloc((size_t)(N + 1) * 4);
    int*      bsum   = (int*)alloc(64 * 4);
    int*      boff   = (int*)alloc(64 * 4);
    float*    dis    = (float*)alloc((size_t)N * 4);
    int*      eoff   = (int*)alloc((size_t)E * 4);
    int*      csrc   = (int*)alloc((size_t)E * 4);
    float*    buf1   = (float*)alloc((size_t)N * 96 * 4);
    float*    buf2   = (float*)alloc((size_t)N * 96 * 4);
    _Float16* hbuf   = (_Float16*)alloc((size_t)N * 96 * 2);
    float*    sums   = (float*)alloc(576 * 4);
    float* sums1 = sums, *sums2 = sums + 192, *sums3 = sums + 384;

    float* out = (float*)d_out;

    const int gE  = cdiv(E, BLK);                       // 3125 blocks
    const int gG  = cdiv(N, 64);                        // 782 gemm blocks
    const int gA  = cdiv((long long)((N + 1) / 2) * 12, BLK);  // 1172 agg blocks
    const int nb  = cdiv(N, 1024);                      // scan blocks (49)

    // CSR build (atomic-free 4-B scatter: slot = rowptr[dst] + eoff)
    zero_int<<<cdiv(N, BLK), BLK, 0, stream>>>(cnt, N);
    count_dst_off<<<gE, BLK, 0, stream>>>(dst, cnt, eoff, E);
    scan1_dis<<<nb, 256, 0, stream>>>(cnt, rowptr, bsum, dis, N);
    scan2z<<<1, 640, 0, stream>>>(bsum, boff, nb, sums);
    scan3<<<cdiv(N, BLK), BLK, 0, stream>>>(rowptr, boff, N, E);
    csr_fill<<<gE, BLK, 0, stream>>>(src, dst, eoff, rowptr, csrc, E);

    // layer 1: MFMA GEMM -> fp16 shadow; dual-node agg
    gemm96m<128, false, false, true, false, false><<<gG, 256, 0, stream>>>(
        x, W1, nullptr, nullptr, nullptr, nullptr, nullptr, hbuf, nullptr, N);
    agg96h2<<<gA, 256, 0, stream>>>((const __half*)hbuf, rowptr, csrc, dis, b1, buf2, N);
    bn_stats96<<<512, 256, 0, stream>>>(buf2, sums1, N);

    // layer 2: BN1 finalize fused in-block; fp16 shadow out
    gemm96m<96, true, false, true, false, false><<<gG, 256, 0, stream>>>(
        buf2, W2, nullptr, sums1, g1, be1, nullptr, hbuf, nullptr, N);
    agg96h2<<<gA, 256, 0, stream>>>((const __half*)hbuf, rowptr, csrc, dis, b2, buf2, N);
    bn_stats96<<<512, 256, 0, stream>>>(buf2, sums2, N);

    // projector linear 1: BN2 finalize fused; fp32 out; BN3 stats fused
    gemm96m<96, true, true, false, true, true><<<gG, 256, 0, stream>>>(
        buf2, Wp1, bp1, sums2, g2, be2, buf1, nullptr, sums3, N);

    // projector linear 2: BN3 finalize fused + bias + L2 normalize
    gemm_finalm<<<gG, 256, 0, stream>>>(buf1, Wp2, bp2, sums3, gp, bep, out, N);
}

// Round 13
// 335.782 us; speedup vs baseline: 1.2405x; 1.0665x over previous
//
#include <hip/hip_runtime.h>
#include <hip/hip_fp16.h>

constexpr int BLK = 256;

static inline int cdiv(long long a, int b) { return (int)((a + b - 1) / b); }

using v8h = __attribute__((ext_vector_type(8))) _Float16;
using v4f = __attribute__((ext_vector_type(4))) float;

// ---------------- utility ----------------

__global__ void zero_int(int* __restrict__ p, int n) {
    for (int i = blockIdx.x * blockDim.x + threadIdx.x; i < n; i += gridDim.x * blockDim.x)
        p[i] = 0;
}

// ---------------- degree / CSR build ----------------

// count in-degree; record per-edge within-node offset as uint16 (deg < 64K)
__global__ void count_dst_off(const int* __restrict__ dst, int* __restrict__ cnt,
                              unsigned short* __restrict__ eoff, int E) {
    for (int i = blockIdx.x * blockDim.x + threadIdx.x; i < E; i += gridDim.x * blockDim.x)
        eoff[i] = (unsigned short)atomicAdd(&cnt[dst[i]], 1);
}

// block scans 1024 elements (256 threads x 4); also emits dis = rsqrt(cnt+1)
__global__ void scan1_dis(const int* __restrict__ cnt, int* __restrict__ rowptr,
                          int* __restrict__ bsum, float* __restrict__ dis, int N) {
    __shared__ int ts[256];
    int tid = threadIdx.x;
    int base = blockIdx.x * 1024 + tid * 4;
    int v[4], s = 0;
#pragma unroll
    for (int i = 0; i < 4; ++i) {
        v[i] = (base + i < N) ? cnt[base + i] : 0;
        s += v[i];
        if (base + i < N) dis[base + i] = rsqrtf((float)v[i] + 1.0f);
    }
    ts[tid] = s;
    __syncthreads();
    for (int off = 1; off < 256; off <<= 1) {
        int t = 0;
        if (tid >= off) t = ts[tid - off];
        __syncthreads();
        if (tid >= off) ts[tid] += t;
        __syncthreads();
    }
    int run = ts[tid] - s;
#pragma unroll
    for (int i = 0; i < 4; ++i) {
        if (base + i < N) rowptr[base + i] = run;
        run += v[i];
    }
    if (tid == 255) bsum[blockIdx.x] = ts[255];
}

// wave shuffle-scan over block sums (nb <= 64) + zero the BN sums buffer
__global__ void scan2z(const int* __restrict__ bsum, int* __restrict__ boff, int nb,
                       float* __restrict__ sums) {
    int tid = threadIdx.x;  // 640 threads
    if (tid < 64) {
        int orig = (tid < nb) ? bsum[tid] : 0;
        int v = orig;
#pragma unroll
        for (int off = 1; off < 64; off <<= 1) {
            int t = __shfl_up(v, off, 64);
            if (tid >= off) v += t;
        }
        if (tid < nb) boff[tid] = v - orig;  // exclusive
    } else if (tid < 64 + 576) {
        sums[tid - 64] = 0.0f;
    }
}

__global__ void scan3(int* __restrict__ rowptr, const int* __restrict__ boff, int N, int E) {
    int i = blockIdx.x * blockDim.x + threadIdx.x;
    if (i < N) rowptr[i] += boff[i >> 10];
    if (i == 0) rowptr[N] = E;
}

// atomic-free scatter of 2-B src index: slot = rowptr[dst] + eoff (bijection)
__global__ void csr_fill(const int* __restrict__ src, const int* __restrict__ dst,
                         const unsigned short* __restrict__ eoff,
                         const int* __restrict__ rowptr,
                         unsigned short* __restrict__ csrc, int E) {
    for (int i = blockIdx.x * blockDim.x + threadIdx.x; i < E; i += gridDim.x * blockDim.x) {
        csrc[rowptr[dst[i]] + (int)eoff[i]] = (unsigned short)src[i];
    }
}

// ---------------- MFMA GEMM: act(in)[N,K] @ W[K,96] (+bias) -----------------
// A: fp32 -> BN+ReLU -> fp16 frags in regs. B: W^T fp16 in LDS (one barrier).
// ACT: BN scale/shift computed in-block from (bnsums, gamma, beta).
// STATS: epilogue accumulates column sum/sumsq into osums.

template <int K, bool ACT, bool BIAS, bool HOUT, bool WOUT, bool STATS>
__global__ __launch_bounds__(256) void gemm96m(const float* __restrict__ in,
                                               const float* __restrict__ W,
                                               const float* __restrict__ bias,
                                               const float* __restrict__ bnsums,
                                               const float* __restrict__ gamma,
                                               const float* __restrict__ beta,
                                               float* __restrict__ out,
                                               _Float16* __restrict__ hout,
                                               float* __restrict__ osums, int N) {
    constexpr int NK = K / 32;
    constexpr int LDK = K + 8;
    __shared__ __align__(16) _Float16 Wt[96 * LDK];
    __shared__ __align__(16) float ssl[ACT ? 192 : 1];
    __shared__ float sb[STATS ? 192 : 1];
    const int tid = threadIdx.x;
    for (int idx = tid; idx < K * 96; idx += 256) {
        int k = idx / 96, n = idx - k * 96;
        Wt[n * LDK + k] = (_Float16)W[idx];
    }
    if (ACT && tid < 96) {
        float inv_n = 1.0f / (float)N;
        float mean = bnsums[tid] * inv_n;
        float var = bnsums[96 + tid] * inv_n - mean * mean;
        float sc = gamma[tid] * rsqrtf(var + 1e-5f);
        ssl[tid] = sc;
        ssl[96 + tid] = beta[tid] - mean * sc;
    }
    if (STATS && tid < 192) sb[tid] = 0.0f;
    __syncthreads();

    const int wave = tid >> 6, lane = tid & 63;
    const int quad = lane >> 4, lm = lane & 15;
    const int rbase = blockIdx.x * 64 + wave * 16;
    int arow = rbase + lm;
    arow = arow < N ? arow : N - 1;

    v8h afr[NK];
#pragma unroll
    for (int kc = 0; kc < NK; ++kc) {
        const float* p = &in[(long long)arow * K + kc * 32 + quad * 8];
        float4 p0 = *(const float4*)p;
        float4 p1 = *(const float4*)(p + 4);
        if (ACT) {
            int kk = kc * 32 + quad * 8;
            float4 sc0 = *(const float4*)&ssl[kk];
            float4 sc1 = *(const float4*)&ssl[kk + 4];
            float4 sh0 = *(const float4*)&ssl[96 + kk];
            float4 sh1 = *(const float4*)&ssl[96 + kk + 4];
            p0.x = fmaxf(fmaf(p0.x, sc0.x, sh0.x), 0.0f);
            p0.y = fmaxf(fmaf(p0.y, sc0.y, sh0.y), 0.0f);
            p0.z = fmaxf(fmaf(p0.z, sc0.z, sh0.z), 0.0f);
            p0.w = fmaxf(fmaf(p0.w, sc0.w, sh0.w), 0.0f);
            p1.x = fmaxf(fmaf(p1.x, sc1.x, sh1.x), 0.0f);
            p1.y = fmaxf(fmaf(p1.y, sc1.y, sh1.y), 0.0f);
            p1.z = fmaxf(fmaf(p1.z, sc1.z, sh1.z), 0.0f);
            p1.w = fmaxf(fmaf(p1.w, sc1.w, sh1.w), 0.0f);
        }
        v8h a;
        a[0] = (_Float16)p0.x; a[1] = (_Float16)p0.y;
        a[2] = (_Float16)p0.z; a[3] = (_Float16)p0.w;
        a[4] = (_Float16)p1.x; a[5] = (_Float16)p1.y;
        a[6] = (_Float16)p1.z; a[7] = (_Float16)p1.w;
        afr[kc] = a;
    }

    v4f acc[6];
#pragma unroll
    for (int t = 0; t < 6; ++t) {
        v4f c = {0.0f, 0.0f, 0.0f, 0.0f};
#pragma unroll
        for (int kc = 0; kc < NK; ++kc) {
            v8h b = *(const v8h*)&Wt[(t * 16 + lm) * LDK + kc * 32 + quad * 8];
            c = __builtin_amdgcn_mfma_f32_16x16x32_f16(afr[kc], b, c, 0, 0, 0);
        }
        acc[t] = c;
    }

    float ls[6], lq[6];
#pragma unroll
    for (int t = 0; t < 6; ++t) { ls[t] = 0.0f; lq[t] = 0.0f; }
#pragma unroll
    for (int t = 0; t < 6; ++t) {
        float bv = BIAS ? bias[t * 16 + lm] : 0.0f;
#pragma unroll
        for (int r = 0; r < 4; ++r) {
            int gr = rbase + quad * 4 + r;
            if (gr < N) {
                float o = acc[t][r] + bv;
                if (WOUT) out[(long long)gr * 96 + t * 16 + lm] = o;
                if (HOUT) hout[(long long)gr * 96 + t * 16 + lm] = (_Float16)o;
                if (STATS) { ls[t] += o; lq[t] += o * o; }
            }
        }
    }
    if (STATS) {
#pragma unroll
        for (int t = 0; t < 6; ++t) {
            ls[t] += __shfl_xor(ls[t], 16);
            ls[t] += __shfl_xor(ls[t], 32);
            lq[t] += __shfl_xor(lq[t], 16);
            lq[t] += __shfl_xor(lq[t], 32);
        }
        if (quad == 0) {
#pragma unroll
            for (int t = 0; t < 6; ++t) {
                atomicAdd(&sb[t * 16 + lm], ls[t]);
                atomicAdd(&sb[96 + t * 16 + lm], lq[t]);
            }
        }
        __syncthreads();
        if (tid < 192) atomicAdd(&osums[tid], sb[tid]);
    }
}

// ---------------- MFMA final GEMM: l2norm(act(in) @ Wp2[96,64] + bp2) -------

__global__ __launch_bounds__(256) void gemm_finalm(const float* __restrict__ in,
                                                   const float* __restrict__ W,
                                                   const float* __restrict__ bias,
                                                   const float* __restrict__ bnsums,
                                                   const float* __restrict__ gamma,
                                                   const float* __restrict__ beta,
                                                   float* __restrict__ out, int N) {
    constexpr int K = 96, NK = 3, LDK = K + 8;
    __shared__ __align__(16) _Float16 Wt[64 * LDK];
    __shared__ __align__(16) float ssl[192];
    const int tid = threadIdx.x;
    for (int idx = tid; idx < K * 64; idx += 256) {
        int k = idx / 64, n = idx - k * 64;
        Wt[n * LDK + k] = (_Float16)W[idx];
    }
    if (tid < 96) {
        float inv_n = 1.0f / (float)N;
        float mean = bnsums[tid] * inv_n;
        float var = bnsums[96 + tid] * inv_n - mean * mean;
        float sc = gamma[tid] * rsqrtf(var + 1e-5f);
        ssl[tid] = sc;
        ssl[96 + tid] = beta[tid] - mean * sc;
    }
    __syncthreads();

    const int wave = tid >> 6, lane = tid & 63;
    const int quad = lane >> 4, lm = lane & 15;
    const int rbase = blockIdx.x * 64 + wave * 16;
    int arow = rbase + lm;
    arow = arow < N ? arow : N - 1;

    v8h afr[NK];
#pragma unroll
    for (int kc = 0; kc < NK; ++kc) {
        const float* p = &in[(long long)arow * K + kc * 32 + quad * 8];
        float4 p0 = *(const float4*)p;
        float4 p1 = *(const float4*)(p + 4);
        int kk = kc * 32 + quad * 8;
        float4 sc0 = *(const float4*)&ssl[kk];
        float4 sc1 = *(const float4*)&ssl[kk + 4];
        float4 sh0 = *(const float4*)&ssl[96 + kk];
        float4 sh1 = *(const float4*)&ssl[96 + kk + 4];
        p0.x = fmaxf(fmaf(p0.x, sc0.x, sh0.x), 0.0f);
        p0.y = fmaxf(fmaf(p0.y, sc0.y, sh0.y), 0.0f);
        p0.z = fmaxf(fmaf(p0.z, sc0.z, sh0.z), 0.0f);
        p0.w = fmaxf(fmaf(p0.w, sc0.w, sh0.w), 0.0f);
        p1.x = fmaxf(fmaf(p1.x, sc1.x, sh1.x), 0.0f);
        p1.y = fmaxf(fmaf(p1.y, sc1.y, sh1.y), 0.0f);
        p1.z = fmaxf(fmaf(p1.z, sc1.z, sh1.z), 0.0f);
        p1.w = fmaxf(fmaf(p1.w, sc1.w, sh1.w), 0.0f);
        v8h a;
        a[0] = (_Float16)p0.x; a[1] = (_Float16)p0.y;
        a[2] = (_Float16)p0.z; a[3] = (_Float16)p0.w;
        a[4] = (_Float16)p1.x; a[5] = (_Float16)p1.y;
        a[6] = (_Float16)p1.z; a[7] = (_Float16)p1.w;
        afr[kc] = a;
    }

    v4f acc[4];
#pragma unroll
    for (int t = 0; t < 4; ++t) {
        v4f c = {0.0f, 0.0f, 0.0f, 0.0f};
#pragma unroll
        for (int kc = 0; kc < NK; ++kc) {
            v8h b = *(const v8h*)&Wt[(t * 16 + lm) * LDK + kc * 32 + quad * 8];
            c = __builtin_amdgcn_mfma_f32_16x16x32_f16(afr[kc], b, c, 0, 0, 0);
        }
        float bv = bias[t * 16 + lm];
        c[0] += bv; c[1] += bv; c[2] += bv; c[3] += bv;
        acc[t] = c;
    }

    float sq[4];
#pragma unroll
    for (int r = 0; r < 4; ++r) {
        float s = acc[0][r] * acc[0][r] + acc[1][r] * acc[1][r] +
                  acc[2][r] * acc[2][r] + acc[3][r] * acc[3][r];
#pragma unroll
        for (int m = 1; m < 16; m <<= 1) s += __shfl_xor(s, m, 64);
        sq[r] = 1.0f / fmaxf(sqrtf(s), 1e-12f);
    }
#pragma unroll
    for (int r = 0; r < 4; ++r) {
        int gr = rbase + quad * 4 + r;
        if (gr < N) {
#pragma unroll
            for (int t = 0; t < 4; ++t)
                out[(long long)gr * 64 + t * 16 + lm] = acc[t][r] * sq[r];
        }
    }
}

// ---------------- CSR pull aggregation (fp16 gather, 2-B edge index) ---------
// out[n] = bias + dis[n]^2 * h(xw[n]) + sum_e dis[s]*dis[n] * h(xw[s])
// 12 threads per node, 8 cols (16 B fp16) each, edge loop unrolled x8/x4.
// R9-proven structure; R11 slicing and R12 dual-node both regressed.

__device__ __forceinline__ void acc_edge(float* acc, const __half2* h, float w) {
#pragma unroll
    for (int k = 0; k < 4; ++k) {
        float2 f = __half22float2(h[k]);
        acc[2 * k + 0] = fmaf(f.x, w, acc[2 * k + 0]);
        acc[2 * k + 1] = fmaf(f.y, w, acc[2 * k + 1]);
    }
}

__global__ __launch_bounds__(256) void agg96h(const __half* __restrict__ hxw,
                                              const int* __restrict__ rowptr,
                                              const unsigned short* __restrict__ csrc,
                                              const float* __restrict__ dis,
                                              const float* __restrict__ bias,
                                              float* __restrict__ out, int N) {
    int idx = blockIdx.x * 256 + threadIdx.x;
    if (idx >= N * 12) return;
    int n = idx / 12, c8 = idx % 12;
    int ch = c8 * 8;
    float dn = dis[n];
    float acc[8];
    {
        float dd = dn * dn;
        float4 g = *(const float4*)&hxw[(long long)n * 96 + ch];
        const __half2* hs = (const __half2*)&g;
#pragma unroll
        for (int k = 0; k < 4; ++k) {
            float2 f = __half22float2(hs[k]);
            acc[2 * k + 0] = fmaf(f.x, dd, bias[ch + 2 * k + 0]);
            acc[2 * k + 1] = fmaf(f.y, dd, bias[ch + 2 * k + 1]);
        }
    }
    int e = rowptr[n], e1 = rowptr[n + 1];
    for (; e + 7 < e1; e += 8) {
        int s[8];
        float w[8];
        float4 g[8];
#pragma unroll
        for (int j = 0; j < 8; ++j) s[j] = csrc[e + j];
#pragma unroll
        for (int j = 0; j < 8; ++j) w[j] = dis[s[j]] * dn;
#pragma unroll
        for (int j = 0; j < 8; ++j)
            g[j] = *(const float4*)&hxw[(long long)s[j] * 96 + ch];
#pragma unroll
        for (int j = 0; j < 8; ++j) acc_edge(acc, (const __half2*)&g[j], w[j]);
    }
    for (; e + 3 < e1; e += 4) {
        int s[4];
        float w[4];
        float4 g[4];
#pragma unroll
        for (int j = 0; j < 4; ++j) s[j] = csrc[e + j];
#pragma unroll
        for (int j = 0; j < 4; ++j) w[j] = dis[s[j]] * dn;
#pragma unroll
        for (int j = 0; j < 4; ++j)
            g[j] = *(const float4*)&hxw[(long long)s[j] * 96 + ch];
#pragma unroll
        for (int j = 0; j < 4; ++j) acc_edge(acc, (const __half2*)&g[j], w[j]);
    }
    for (; e < e1; ++e) {
        int s0 = csrc[e];
        float w0 = dis[s0] * dn;
        float4 g0 = *(const float4*)&hxw[(long long)s0 * 96 + ch];
        acc_edge(acc, (const __half2*)&g0, w0);
    }
    float4 o0, o1;
    o0.x = acc[0]; o0.y = acc[1]; o0.z = acc[2]; o0.w = acc[3];
    o1.x = acc[4]; o1.y = acc[5]; o1.z = acc[6]; o1.w = acc[7];
    *(float4*)&out[(long long)n * 96 + ch] = o0;
    *(float4*)&out[(long long)n * 96 + ch + 4] = o1;
}

// ---------------- BN stats (coalesced grid-stride, for agg outputs) ----------

__global__ __launch_bounds__(256) void bn_stats96(const float* __restrict__ h,
                                                  float* __restrict__ sums, int N) {
    __shared__ float sb[192];
    const int tid = threadIdx.x;
    if (tid < 192) sb[tid] = 0.0f;
    __syncthreads();
    int g = blockIdx.x * 256 + tid;
    int total = N * 24, stride = gridDim.x * 256;  // stride multiple of 24
    float4 s4 = {0, 0, 0, 0}, q4 = {0, 0, 0, 0};
    int c4 = g % 24;
    for (int i = g; i < total; i += stride) {
        int n = i / 24;
        float4 v = *(const float4*)&h[n * 96 + 4 * c4];
        s4.x += v.x; s4.y += v.y; s4.z += v.z; s4.w += v.w;
        q4.x += v.x * v.x; q4.y += v.y * v.y; q4.z += v.z * v.z; q4.w += v.w * v.w;
    }
    atomicAdd(&sb[4 * c4 + 0], s4.x);
    atomicAdd(&sb[4 * c4 + 1], s4.y);
    atomicAdd(&sb[4 * c4 + 2], s4.z);
    atomicAdd(&sb[4 * c4 + 3], s4.w);
    atomicAdd(&sb[96 + 4 * c4 + 0], q4.x);
    atomicAdd(&sb[96 + 4 * c4 + 1], q4.y);
    atomicAdd(&sb[96 + 4 * c4 + 2], q4.z);
    atomicAdd(&sb[96 + 4 * c4 + 3], q4.w);
    __syncthreads();
    if (tid < 192) atomicAdd(&sums[tid], sb[tid]);
}

// ---------------- launch ----------------

extern "C" void kernel_launch(void* const* d_in, const int* in_sizes, int n_in,
                              void* d_out, int out_size, void* d_ws, size_t ws_size,
                              hipStream_t stream) {
    const float* x   = (const float*)d_in[0];
    const int*   ei  = (const int*)d_in[1];
    const float* W1  = (const float*)d_in[2];
    const float* b1  = (const float*)d_in[3];
    const float* g1  = (const float*)d_in[4];
    const float* be1 = (const float*)d_in[5];
    const float* W2  = (const float*)d_in[6];
    const float* b2  = (const float*)d_in[7];
    const float* g2  = (const float*)d_in[8];
    const float* be2 = (const float*)d_in[9];
    const float* Wp1 = (const float*)d_in[10];
    const float* bp1 = (const float*)d_in[11];
    const float* gp  = (const float*)d_in[12];
    const float* bep = (const float*)d_in[13];
    const float* Wp2 = (const float*)d_in[14];
    const float* bp2 = (const float*)d_in[15];

    const int N = in_sizes[0] / 128;   // 50000 (< 2^16 -> uint16 indices ok)
    const int E = in_sizes[1] / 2;     // 800000
    const int* src = ei;
    const int* dst = ei + E;

    // workspace layout (~50 MB)
    char* w = (char*)d_ws;
    auto alloc = [&](size_t bytes) { char* p = w; w += (bytes + 15) & ~size_t(15); return p; };
    int*            cnt    = (int*)alloc((size_t)N * 4);
    int*            rowptr = (int*)alloc((size_t)(N + 1) * 4);
    int*            bsum   = (int*)alloc(64 * 4);
    int*            boff   = (int*)alloc(64 * 4);
    float*          dis    = (float*)alloc((size_t)N * 4);
    unsigned short* eoff   = (unsigned short*)alloc((size_t)E * 2);
    unsigned short* csrc   = (unsigned short*)alloc((size_t)E * 2);
    float*          buf1   = (float*)alloc((size_t)N * 96 * 4);
    float*          buf2   = (float*)alloc((size_t)N * 96 * 4);
    _Float16*       hbuf   = (_Float16*)alloc((size_t)N * 96 * 2);
    float*          sums   = (float*)alloc(576 * 4);
    float* sums1 = sums, *sums2 = sums + 192, *sums3 = sums + 384;

    float* out = (float*)d_out;

    const int gE  = cdiv(E, BLK);                  // 3125 blocks
    const int gG  = cdiv(N, 64);                   // 782 gemm blocks
    const int gA  = cdiv((long long)N * 12, BLK);  // 2344 agg blocks
    const int nb  = cdiv(N, 1024);                 // scan blocks (49)

    // CSR build (atomic-free 2-B scatter: slot = rowptr[dst] + eoff)
    zero_int<<<cdiv(N, BLK), BLK, 0, stream>>>(cnt, N);
    count_dst_off<<<gE, BLK, 0, stream>>>(dst, cnt, eoff, E);
    scan1_dis<<<nb, 256, 0, stream>>>(cnt, rowptr, bsum, dis, N);
    scan2z<<<1, 640, 0, stream>>>(bsum, boff, nb, sums);
    scan3<<<cdiv(N, BLK), BLK, 0, stream>>>(rowptr, boff, N, E);
    csr_fill<<<gE, BLK, 0, stream>>>(src, dst, eoff, rowptr, csrc, E);

    // layer 1: MFMA GEMM -> fp16 shadow; single-node agg (R9 form)
    gemm96m<128, false, false, true, false, false><<<gG, 256, 0, stream>>>(
        x, W1, nullptr, nullptr, nullptr, nullptr, nullptr, hbuf, nullptr, N);
    agg96h<<<gA, 256, 0, stream>>>((const __half*)hbuf, rowptr, csrc, dis, b1, buf2, N);
    bn_stats96<<<512, 256, 0, stream>>>(buf2, sums1, N);

    // layer 2: BN1 finalize fused in-block; fp16 shadow out
    gemm96m<96, true, false, true, false, false><<<gG, 256, 0, stream>>>(
        buf2, W2, nullptr, sums1, g1, be1, nullptr, hbuf, nullptr, N);
    agg96h<<<gA, 256, 0, stream>>>((const __half*)hbuf, rowptr, csrc, dis, b2, buf2, N);
    bn_stats96<<<512, 256, 0, stream>>>(buf2, sums2, N);

    // projector linear 1: BN2 finalize fused; fp32 out; BN3 stats fused
    gemm96m<96, true, true, false, true, true><<<gG, 256, 0, stream>>>(
        buf2, Wp1, bp1, sums2, g2, be2, buf1, nullptr, sums3, N);

    // projector linear 2: BN3 finalize fused + bias + L2 normalize
    gemm_finalm<<<gG, 256, 0, stream>>>(buf1, Wp2, bp2, sums3, gp, bep, out, N);
}